// Round 5
// baseline (167.749 us; speedup 1.0000x reference)
//
#include <hip/hip_runtime.h>
#include <math.h>

#define TB 2
#define TT 2048
#define NH 16
#define HD 64
#define HSZ 1024
#define NROW 65536          // total q-rows * heads = B*T*NH
#define OPHALF 4194304      // NROW * HD, elements per split partial

typedef float floatx4 __attribute__((ext_vector_type(4)));
typedef __bf16 bf16x4 __attribute__((ext_vector_type(4)));
typedef __bf16 bf16x8 __attribute__((ext_vector_type(8)));

#define LOG2E  1.4426950408889634f
#define NEGF   (-0.4152410118609203f)   // -log2(10000)/32
#define INV2PI 0.15915494309189535f

// ============ phase 1: fused prep — RoPE-K pack + V transpose-pack ============
__global__ __launch_bounds__(256)
void prep_kernel(const float* __restrict__ K, const float* __restrict__ V,
                 __bf16* __restrict__ Kp, __bf16* __restrict__ Vp) {
    int blk = blockIdx.x;               // bh*32 + kt, 1024 blocks
    int kt = blk & 31;
    int bh = blk >> 5;
    int b = bh >> 4, h = bh & 15;
    int tid = threadIdx.x;

    // ---- K part: thread -> (key=tid>>2, dim-octet qq=tid&3); 16 lines/instr ----
    {
        int key = tid >> 2, qq = tid & 3;
        int tglob = kt * 64 + key;
        const float* krow = K + ((size_t)(b * TT + tglob)) * HSZ + h * HD + qq * 8;
        float x0[8], x1[8];
        *(floatx4*)&x0[0] = *(const floatx4*)&krow[0];
        *(floatx4*)&x0[4] = *(const floatx4*)&krow[4];
        *(floatx4*)&x1[0] = *(const floatx4*)&krow[32];
        *(floatx4*)&x1[4] = *(const floatx4*)&krow[36];
        bf16x8 y0, y1;
        #pragma unroll
        for (int j = 0; j < 8; ++j) {
            float freq = exp2f((float)(qq * 8 + j) * NEGF);
            float rv = (float)tglob * freq * INV2PI;
            rv -= floorf(rv);
            float s = __builtin_amdgcn_sinf(rv);
            float c = __builtin_amdgcn_cosf(rv);
            y0[j] = (__bf16)(x0[j] * c - x1[j] * s);
            y1[j] = (__bf16)(x1[j] * c + x0[j] * s);
        }
        size_t base = ((size_t)blk * 4 + (key & 3)) * 1024 + (size_t)(qq * 16 + (key >> 2)) * 8;
        *(bf16x8*)(Kp + base)       = y0;
        *(bf16x8*)(Kp + base + 512) = y1;
    }

    // ---- V part: transpose 64x64 via LDS ----
    __shared__ __bf16 lt[64][72];
    {
        int vkey = tid >> 2, dg = (tid & 3) * 16;
        const float* vrow = V + ((size_t)(b * TT + kt * 64 + vkey)) * HSZ + h * HD + dg;
        floatx4 v0 = *(const floatx4*)&vrow[0];
        floatx4 v1 = *(const floatx4*)&vrow[4];
        floatx4 v2 = *(const floatx4*)&vrow[8];
        floatx4 v3 = *(const floatx4*)&vrow[12];
        #pragma unroll
        for (int j = 0; j < 4; ++j) {
            lt[dg + j][vkey]      = (__bf16)v0[j];
            lt[dg + 4 + j][vkey]  = (__bf16)v1[j];
            lt[dg + 8 + j][vkey]  = (__bf16)v2[j];
            lt[dg + 12 + j][vkey] = (__bf16)v3[j];
        }
    }
    __syncthreads();
    #pragma unroll
    for (int ss = 0; ss < 2; ++ss) {
        int s = tid + ss * 256;
        int hg = s >> 6;
        int l = s & 63;
        int lq = l >> 4, lr = l & 15;
        int h2 = hg >> 2, g = hg & 3;
        bf16x8 o = *(const bf16x8*)&lt[g * 16 + lr][h2 * 32 + lq * 8];
        *(bf16x8*)(Vp + (size_t)blk * 4096 + (size_t)hg * 512 + (size_t)l * 8) = o;
    }
}

// ============ phase 2: split-K flash attention, static shift ============
__global__ __launch_bounds__(256)
void attn_kernel(const float* __restrict__ Q, const __bf16* __restrict__ Kp,
                 const __bf16* __restrict__ Vp, __bf16* __restrict__ Op,
                 float* __restrict__ lp) {
    int blk = blockIdx.x;               // bh*64 + qtile*2 + s, 2048 blocks
    int s = blk & 1;
    int qtile = (blk >> 1) & 31;
    int bh = blk >> 6;
    int b = bh >> 4, h = bh & 15;
    int tid = threadIdx.x;
    int wave = tid >> 6, lane = tid & 63;
    int lane15 = lane & 15, quad = lane >> 4;

    __shared__ __align__(16) __bf16 sP[4][16][72];

    const float scale2 = 0.125f * LOG2E;
    const float slope2 = exp2f(-0.5f * (float)(h + 1)) * LOG2E;
    const float ms     = slope2 * 2047.0f + 20.0f;   // static log2-domain shift

    // ---- Q load + RoPE into A fragments ----
    int t_q = qtile * 64 + wave * 16 + lane15;
    int d0 = quad * 8;
    const float* qrow = Q + ((size_t)(b * TT + t_q) * HSZ) + h * HD;
    float q0[8], q1[8];
    *(floatx4*)&q0[0] = *(const floatx4*)&qrow[d0];
    *(floatx4*)&q0[4] = *(const floatx4*)&qrow[d0 + 4];
    *(floatx4*)&q1[0] = *(const floatx4*)&qrow[d0 + 32];
    *(floatx4*)&q1[4] = *(const floatx4*)&qrow[d0 + 36];
    bf16x8 aQ0, aQ1;
    #pragma unroll
    for (int j = 0; j < 8; ++j) {
        float freq = exp2f((float)(d0 + j) * NEGF);
        float rv = (float)t_q * freq * INV2PI;
        rv -= floorf(rv);
        float sn = __builtin_amdgcn_sinf(rv);
        float cs = __builtin_amdgcn_cosf(rv);
        aQ0[j] = (__bf16)((q0[j] * cs - q1[j] * sn) * scale2);
        aQ1[j] = (__bf16)((q1[j] * cs + q0[j] * sn) * scale2);
    }

    float slk2[4];
    #pragma unroll
    for (int nt = 0; nt < 4; ++nt)
        slk2[nt] = slope2 * (float)(4 * lane15 + nt) - ms;
    const float dstep = slope2 * 64.0f;

    floatx4 O0 = {0.f,0.f,0.f,0.f}, O1 = O0, O2 = O0, O3 = O0;
    float lrow[4] = {0.f, 0.f, 0.f, 0.f};

    const __bf16* Kb = Kp + (size_t)bh * (TT * HD) + (size_t)lane * 8;
    const __bf16* Vb = Vp + (size_t)bh * (TT * HD) + (size_t)lane * 8;

    for (int kt = s * 16; kt < s * 16 + 16; ++kt) {
        const __bf16* kbase = Kb + (size_t)kt * 4096;
        const __bf16* vbase = Vb + (size_t)kt * 4096;

        // K fragments (consumed just below), V fragments (consumed after softmax)
        bf16x8 bk[4][2];
        #pragma unroll
        for (int nt = 0; nt < 4; ++nt) {
            bk[nt][0] = *(const bf16x8*)(kbase + nt * 1024);
            bk[nt][1] = *(const bf16x8*)(kbase + nt * 1024 + 512);
        }
        bf16x8 bv[2][4];
        #pragma unroll
        for (int hg = 0; hg < 8; ++hg)
            bv[hg >> 2][hg & 3] = *(const bf16x8*)(vbase + hg * 512);

        // ---- QK^T + bias + exp2 (base-2, static shift; no running max) ----
        float P[4][4];
        float biask = dstep * (float)kt;
        #pragma unroll
        for (int nt = 0; nt < 4; ++nt) {
            floatx4 acc = {0.f,0.f,0.f,0.f};
            acc = __builtin_amdgcn_mfma_f32_16x16x32_bf16(aQ0, bk[nt][0], acc, 0, 0, 0);
            acc = __builtin_amdgcn_mfma_f32_16x16x32_bf16(aQ1, bk[nt][1], acc, 0, 0, 0);
            float bias = slk2[nt] + biask;
            #pragma unroll
            for (int r = 0; r < 4; ++r)
                P[nt][r] = __builtin_amdgcn_exp2f(acc[r] + bias);
        }

        // ---- P -> LDS (one b64 per row), accumulate row sums ----
        #pragma unroll
        for (int r = 0; r < 4; ++r) {
            lrow[r] += (P[0][r] + P[1][r]) + (P[2][r] + P[3][r]);
            bf16x4 pp;
            pp[0] = (__bf16)P[0][r]; pp[1] = (__bf16)P[1][r];
            pp[2] = (__bf16)P[2][r]; pp[3] = (__bf16)P[3][r];
            *(bf16x4*)&sP[wave][quad * 4 + r][4 * lane15] = pp;
        }

        // ---- PV ----
        #pragma unroll
        for (int h2 = 0; h2 < 2; ++h2) {
            bf16x8 aP = *(const bf16x8*)&sP[wave][lane15][h2 * 32 + quad * 8];
            O0 = __builtin_amdgcn_mfma_f32_16x16x32_bf16(aP, bv[h2][0], O0, 0, 0, 0);
            O1 = __builtin_amdgcn_mfma_f32_16x16x32_bf16(aP, bv[h2][1], O1, 0, 0, 0);
            O2 = __builtin_amdgcn_mfma_f32_16x16x32_bf16(aP, bv[h2][2], O2, 0, 0, 0);
            O3 = __builtin_amdgcn_mfma_f32_16x16x32_bf16(aP, bv[h2][3], O3, 0, 0, 0);
        }
    }

    // ---- epilogue: reduce l, store UNNORMALIZED bf16 partial O + fp32 l ----
    int q_glb = qtile * 64 + wave * 16 + quad * 4;
    #pragma unroll
    for (int r = 0; r < 4; ++r) {
        float l = lrow[r];
        l += __shfl_xor(l, 1);
        l += __shfl_xor(l, 2);
        l += __shfl_xor(l, 4);
        l += __shfl_xor(l, 8);
        int rid = (b * TT + q_glb + r) * NH + h;
        size_t base = ((size_t)s * NROW + rid) * HD + lane15;
        Op[base +  0] = (__bf16)O0[r];
        Op[base + 16] = (__bf16)O1[r];
        Op[base + 32] = (__bf16)O2[r];
        Op[base + 48] = (__bf16)O3[r];
        if (lane15 == 0) lp[s * NROW + rid] = l;
    }
}

// ============ phase 3: combine splits ============
__global__ __launch_bounds__(256)
void reduce_kernel(const __bf16* __restrict__ Op, const float* __restrict__ lp,
                   float* __restrict__ Out) {
    int i = blockIdx.x * 256 + threadIdx.x;    // 1048576 threads, one float4 each
    size_t f = (size_t)i * 4;
    int rid = (int)(f >> 6);
    bf16x4 a = *(const bf16x4*)(Op + f);
    bf16x4 c = *(const bf16x4*)(Op + OPHALF + f);
    float inv = 1.0f / (lp[rid] + lp[NROW + rid]);
    floatx4 o;
    #pragma unroll
    for (int j = 0; j < 4; ++j)
        o[j] = ((float)a[j] + (float)c[j]) * inv;
    *(floatx4*)(Out + f) = o;
}

extern "C" void kernel_launch(void* const* d_in, const int* in_sizes, int n_in,
                              void* d_out, int out_size, void* d_ws, size_t ws_size,
                              hipStream_t stream) {
    const float* q = (const float*)d_in[0];
    const float* k = (const float*)d_in[1];
    const float* v = (const float*)d_in[2];
    float* out = (float*)d_out;

    char* ws = (char*)d_ws;
    __bf16* Kp = (__bf16*)ws;                                  // 8 MB
    __bf16* Vp = (__bf16*)(ws + (size_t)8 * 1024 * 1024);      // 8 MB
    __bf16* Op = (__bf16*)(ws + (size_t)16 * 1024 * 1024);     // 16 MB (2 splits bf16)
    float*  lp = (float*)(ws + (size_t)33 * 1024 * 1024);      // 512 KB

    prep_kernel<<<dim3(TB * NH * (TT / 64)), 256, 0, stream>>>(k, v, Kp, Vp);
    attn_kernel<<<dim3(TB * NH * (TT / 64) * 2), 256, 0, stream>>>(q, Kp, Vp, Op, lp);
    reduce_kernel<<<dim3((TB * TT * HSZ / 4) / 256), 256, 0, stream>>>(Op, lp, out);
}

// Round 6
// 140.505 us; speedup vs baseline: 1.1939x; 1.1939x over previous
//
#include <hip/hip_runtime.h>
#include <math.h>

#define TB 2
#define TT 2048
#define NH 16
#define HD 64
#define HSZ 1024
#define NROW 65536          // B*T*NH q-rows
#define OPHALF 4194304      // NROW * HD

typedef float floatx4 __attribute__((ext_vector_type(4)));
typedef __bf16 bf16x4 __attribute__((ext_vector_type(4)));
typedef __bf16 bf16x8 __attribute__((ext_vector_type(8)));

#define LOG2E  1.4426950408889634f
#define NEGF   (-0.4152410118609203f)   // -log2(10000)/32
#define INV2PI 0.15915494309189535f

// ============ phase 1: fused prep — RoPE-K pack + V transpose-pack ============
__global__ __launch_bounds__(256)
void prep_kernel(const float* __restrict__ K, const float* __restrict__ V,
                 __bf16* __restrict__ Kp, __bf16* __restrict__ Vp) {
    int blk = blockIdx.x;               // bh*32 + kt, 1024 blocks
    int kt = blk & 31;
    int bh = blk >> 5;
    int b = bh >> 4, h = bh & 15;
    int tid = threadIdx.x;

    // ---- K part: thread -> (key=tid>>2, dim-octet qq=tid&3) ----
    {
        int key = tid >> 2, qq = tid & 3;
        int tglob = kt * 64 + key;
        const float* krow = K + ((size_t)(b * TT + tglob)) * HSZ + h * HD + qq * 8;
        float x0[8], x1[8];
        *(floatx4*)&x0[0] = *(const floatx4*)&krow[0];
        *(floatx4*)&x0[4] = *(const floatx4*)&krow[4];
        *(floatx4*)&x1[0] = *(const floatx4*)&krow[32];
        *(floatx4*)&x1[4] = *(const floatx4*)&krow[36];
        bf16x8 y0, y1;
        #pragma unroll
        for (int j = 0; j < 8; ++j) {
            float freq = exp2f((float)(qq * 8 + j) * NEGF);
            float rv = (float)tglob * freq * INV2PI;
            rv -= floorf(rv);
            float s = __builtin_amdgcn_sinf(rv);
            float c = __builtin_amdgcn_cosf(rv);
            y0[j] = (__bf16)(x0[j] * c - x1[j] * s);
            y1[j] = (__bf16)(x1[j] * c + x0[j] * s);
        }
        size_t base = ((size_t)blk * 4 + (key & 3)) * 1024 + (size_t)(qq * 16 + (key >> 2)) * 8;
        *(bf16x8*)(Kp + base)       = y0;
        *(bf16x8*)(Kp + base + 512) = y1;
    }

    // ---- V part: transpose 64x64 via LDS ----
    __shared__ __bf16 lt[64][72];
    {
        int vkey = tid >> 2, dg = (tid & 3) * 16;
        const float* vrow = V + ((size_t)(b * TT + kt * 64 + vkey)) * HSZ + h * HD + dg;
        floatx4 v0 = *(const floatx4*)&vrow[0];
        floatx4 v1 = *(const floatx4*)&vrow[4];
        floatx4 v2 = *(const floatx4*)&vrow[8];
        floatx4 v3 = *(const floatx4*)&vrow[12];
        #pragma unroll
        for (int j = 0; j < 4; ++j) {
            lt[dg + j][vkey]      = (__bf16)v0[j];
            lt[dg + 4 + j][vkey]  = (__bf16)v1[j];
            lt[dg + 8 + j][vkey]  = (__bf16)v2[j];
            lt[dg + 12 + j][vkey] = (__bf16)v3[j];
        }
    }
    __syncthreads();
    #pragma unroll
    for (int ss = 0; ss < 2; ++ss) {
        int s = tid + ss * 256;
        int hg = s >> 6;
        int l = s & 63;
        int lq = l >> 4, lr = l & 15;
        int h2 = hg >> 2, g = hg & 3;
        bf16x8 o = *(const bf16x8*)&lt[g * 16 + lr][h2 * 32 + lq * 8];
        *(bf16x8*)(Vp + (size_t)blk * 4096 + (size_t)hg * 512 + (size_t)l * 8) = o;
    }
}

// ============ phase 2: split-K flash attention, 64 q-rows per wave ============
__global__ __launch_bounds__(256, 2)
void attn_kernel(const float* __restrict__ Q, const __bf16* __restrict__ Kp,
                 const __bf16* __restrict__ Vp, __bf16* __restrict__ Op,
                 float* __restrict__ lp) {
    int blk = blockIdx.x;               // bh*16 + qb*2 + s, 512 blocks
    int s = blk & 1;
    int qb = (blk >> 1) & 7;            // 8 q-blocks of 256 rows
    int bh = blk >> 4;
    int b = bh >> 4, h = bh & 15;
    int tid = threadIdx.x;
    int wave = tid >> 6, lane = tid & 63;
    int lane15 = lane & 15, quad = lane >> 4;

    // per-wave, per-qf P round-trip tiles; no __syncthreads anywhere
    __shared__ __align__(16) __bf16 sP[4][4][16][72];   // 36864 B

    const float scale2 = 0.125f * LOG2E;
    const float slope2 = exp2f(-0.5f * (float)(h + 1)) * LOG2E;
    const float ms     = slope2 * 2047.0f + 20.0f;      // static log2-domain shift

    // ---- Q load + RoPE into 4 A-fragment pairs (64 q-rows/wave) ----
    int qbase = qb * 256 + wave * 64;
    int d0 = quad * 8;
    bf16x8 aQ0[4], aQ1[4];
    #pragma unroll
    for (int qf = 0; qf < 4; ++qf) {
        int t_q = qbase + qf * 16 + lane15;
        const float* qrow = Q + ((size_t)(b * TT + t_q) * HSZ) + h * HD;
        float q0[8], q1[8];
        *(floatx4*)&q0[0] = *(const floatx4*)&qrow[d0];
        *(floatx4*)&q0[4] = *(const floatx4*)&qrow[d0 + 4];
        *(floatx4*)&q1[0] = *(const floatx4*)&qrow[d0 + 32];
        *(floatx4*)&q1[4] = *(const floatx4*)&qrow[d0 + 36];
        #pragma unroll
        for (int j = 0; j < 8; ++j) {
            float freq = exp2f((float)(d0 + j) * NEGF);
            float rv = (float)t_q * freq * INV2PI;
            rv -= floorf(rv);
            float sn = __builtin_amdgcn_sinf(rv);
            float cs = __builtin_amdgcn_cosf(rv);
            aQ0[qf][j] = (__bf16)((q0[j] * cs - q1[j] * sn) * scale2);
            aQ1[qf][j] = (__bf16)((q1[j] * cs + q0[j] * sn) * scale2);
        }
    }

    float slk2[4];
    #pragma unroll
    for (int nt = 0; nt < 4; ++nt)
        slk2[nt] = slope2 * (float)(4 * lane15 + nt) - ms;
    const float dstep = slope2 * 64.0f;

    floatx4 O[4][4];
    float lrow[4][4];
    #pragma unroll
    for (int qf = 0; qf < 4; ++qf)
        #pragma unroll
        for (int r = 0; r < 4; ++r) {
            O[qf][r] = (floatx4){0.f, 0.f, 0.f, 0.f};
            lrow[qf][r] = 0.f;
        }

    const __bf16* Kb = Kp + (size_t)bh * (TT * HD) + (size_t)lane * 8;
    const __bf16* Vb = Vp + (size_t)bh * (TT * HD) + (size_t)lane * 8;

    const int kt0 = s * 16, kt1 = s * 16 + 16;

    // prologue: K fragments for first tile
    bf16x8 bk[4][2];
    {
        const __bf16* kbase = Kb + (size_t)kt0 * 4096;
        #pragma unroll
        for (int nt = 0; nt < 4; ++nt) {
            bk[nt][0] = *(const bf16x8*)(kbase + nt * 1024);
            bk[nt][1] = *(const bf16x8*)(kbase + nt * 1024 + 512);
        }
    }

    #pragma unroll 1
    for (int kt = kt0; kt < kt1; ++kt) {
        // ---- V fragments for this tile (consumed in phase 2: latency hidden) ----
        const __bf16* vbase = Vb + (size_t)kt * 4096;
        bf16x8 bv[2][4];
        #pragma unroll
        for (int hg = 0; hg < 8; ++hg)
            bv[hg >> 2][hg & 3] = *(const bf16x8*)(vbase + hg * 512);

        // ---- phase 1: QK^T + exp2 + sP, for all 4 q-fragments ----
        float biask = dstep * (float)kt;
        #pragma unroll
        for (int qf = 0; qf < 4; ++qf) {
            float P[4][4];
            #pragma unroll
            for (int nt = 0; nt < 4; ++nt) {
                floatx4 acc = {0.f, 0.f, 0.f, 0.f};
                acc = __builtin_amdgcn_mfma_f32_16x16x32_bf16(aQ0[qf], bk[nt][0], acc, 0, 0, 0);
                acc = __builtin_amdgcn_mfma_f32_16x16x32_bf16(aQ1[qf], bk[nt][1], acc, 0, 0, 0);
                float bias = slk2[nt] + biask;
                #pragma unroll
                for (int r = 0; r < 4; ++r)
                    P[nt][r] = __builtin_amdgcn_exp2f(acc[r] + bias);
            }
            #pragma unroll
            for (int r = 0; r < 4; ++r) {
                lrow[qf][r] += (P[0][r] + P[1][r]) + (P[2][r] + P[3][r]);
                bf16x4 pp;
                pp[0] = (__bf16)P[0][r]; pp[1] = (__bf16)P[1][r];
                pp[2] = (__bf16)P[2][r]; pp[3] = (__bf16)P[3][r];
                *(bf16x4*)&sP[wave][qf][quad * 4 + r][4 * lane15] = pp;
            }
        }

        // ---- prefetch K fragments for next tile (hidden under phase 2) ----
        if (kt + 1 < kt1) {
            const __bf16* kbase = Kb + (size_t)(kt + 1) * 4096;
            #pragma unroll
            for (int nt = 0; nt < 4; ++nt) {
                bk[nt][0] = *(const bf16x8*)(kbase + nt * 1024);
                bk[nt][1] = *(const bf16x8*)(kbase + nt * 1024 + 512);
            }
        }

        // ---- phase 2: PV for all 4 q-fragments ----
        #pragma unroll
        for (int qf = 0; qf < 4; ++qf) {
            #pragma unroll
            for (int h2 = 0; h2 < 2; ++h2) {
                bf16x8 aP = *(const bf16x8*)&sP[wave][qf][lane15][h2 * 32 + quad * 8];
                O[qf][0] = __builtin_amdgcn_mfma_f32_16x16x32_bf16(aP, bv[h2][0], O[qf][0], 0, 0, 0);
                O[qf][1] = __builtin_amdgcn_mfma_f32_16x16x32_bf16(aP, bv[h2][1], O[qf][1], 0, 0, 0);
                O[qf][2] = __builtin_amdgcn_mfma_f32_16x16x32_bf16(aP, bv[h2][2], O[qf][2], 0, 0, 0);
                O[qf][3] = __builtin_amdgcn_mfma_f32_16x16x32_bf16(aP, bv[h2][3], O[qf][3], 0, 0, 0);
            }
        }
    }

    // ---- epilogue: reduce l, store UNNORMALIZED bf16 partial O + fp32 l ----
    #pragma unroll
    for (int qf = 0; qf < 4; ++qf) {
        int q_glb = qbase + qf * 16 + quad * 4;
        #pragma unroll
        for (int r = 0; r < 4; ++r) {
            float l = lrow[qf][r];
            l += __shfl_xor(l, 1);
            l += __shfl_xor(l, 2);
            l += __shfl_xor(l, 4);
            l += __shfl_xor(l, 8);
            int rid = (b * TT + q_glb + r) * NH + h;
            size_t base = ((size_t)s * NROW + rid) * HD + lane15;
            Op[base +  0] = (__bf16)O[qf][0][r];
            Op[base + 16] = (__bf16)O[qf][1][r];
            Op[base + 32] = (__bf16)O[qf][2][r];
            Op[base + 48] = (__bf16)O[qf][3][r];
            if (lane15 == 0) lp[s * NROW + rid] = l;
        }
    }
}

// ============ phase 3: combine splits ============
__global__ __launch_bounds__(256)
void reduce_kernel(const __bf16* __restrict__ Op, const float* __restrict__ lp,
                   float* __restrict__ Out) {
    int i = blockIdx.x * 256 + threadIdx.x;    // 1048576 threads, one float4 each
    size_t f = (size_t)i * 4;
    int rid = (int)(f >> 6);
    bf16x4 a = *(const bf16x4*)(Op + f);
    bf16x4 c = *(const bf16x4*)(Op + OPHALF + f);
    float inv = 1.0f / (lp[rid] + lp[NROW + rid]);
    floatx4 o;
    #pragma unroll
    for (int j = 0; j < 4; ++j)
        o[j] = ((float)a[j] + (float)c[j]) * inv;
    *(floatx4*)(Out + f) = o;
}

extern "C" void kernel_launch(void* const* d_in, const int* in_sizes, int n_in,
                              void* d_out, int out_size, void* d_ws, size_t ws_size,
                              hipStream_t stream) {
    const float* q = (const float*)d_in[0];
    const float* k = (const float*)d_in[1];
    const float* v = (const float*)d_in[2];
    float* out = (float*)d_out;

    char* ws = (char*)d_ws;
    __bf16* Kp = (__bf16*)ws;                                  // 8 MB
    __bf16* Vp = (__bf16*)(ws + (size_t)8 * 1024 * 1024);      // 8 MB
    __bf16* Op = (__bf16*)(ws + (size_t)16 * 1024 * 1024);     // 16 MB (2 splits bf16)
    float*  lp = (float*)(ws + (size_t)33 * 1024 * 1024);      // 512 KB

    prep_kernel<<<dim3(TB * NH * (TT / 64)), 256, 0, stream>>>(k, v, Kp, Vp);
    attn_kernel<<<dim3(TB * NH * 16), 256, 0, stream>>>(q, Kp, Vp, Op, lp);
    reduce_kernel<<<dim3((TB * TT * HSZ / 4) / 256), 256, 0, stream>>>(Op, lp, out);
}